// Round 1
// baseline (891.269 us; speedup 1.0000x reference)
//
#include <hip/hip_runtime.h>

// Single-layer GRU, PyTorch semantics, gate order (r,z,n), h0=0.
// T=512, B=1024, I=64, H=64, fp32.
//
// Parallelization: one block per batch row (recurrence independent across batch).
// Block = 192 threads = 3 waves; wave g in {0:r, 1:z, 2:n}; lane j = hidden unit.
// Each thread keeps its two weight rows (W_ih[g*64+j][:], W_hh[g*64+j][:]) in
// 128 VGPRs (fully unrolled, compile-time indices). Per timestep:
//   wave2 stages x_t into LDS (x_{t+1} prefetched in regs to hide HBM latency),
//   all threads: 128-long dot (x||h) vs. their W rows (LDS broadcast float4 reads),
//   waves 1/2 post pre-activations to LDS, wave 0 combines gates, updates h,
//   writes output. Two barriers per step.

#define T_STEPS 512
#define BATCH   1024
#define IDIM    64
#define HDIM    64

__global__ __launch_bounds__(192, 1)
void gru_fused_kernel(const float* __restrict__ X,     // [T,B,I]
                      const float* __restrict__ W_ih,  // [192,64]
                      const float* __restrict__ W_hh,  // [192,64]
                      const float* __restrict__ b_ih,  // [192]
                      const float* __restrict__ b_hh,  // [192]
                      float* __restrict__ out)         // [T*B*H] ++ [B*H]
{
    const int tid  = threadIdx.x;
    const int g    = tid >> 6;       // 0:r 1:z 2:n
    const int j    = tid & 63;       // hidden unit
    const int gr   = g * 64 + j;     // gate row in [0,192)
    const int brow = blockIdx.x;     // batch row

    __shared__ __align__(16) float v[128];   // [0:64) = x_t, [64:128) = h_{t-1}
    __shared__ float exZ[64];
    __shared__ float exNX[64];
    __shared__ float exNH[64];

    // ---- Load weight rows into registers (static indices only) ----
    float w[128];
    {
        const float4* wi = (const float4*)(W_ih + gr * 64);
        const float4* wh = (const float4*)(W_hh + gr * 64);
        #pragma unroll
        for (int k = 0; k < 16; ++k) {
            float4 a = wi[k];
            w[4*k+0] = a.x; w[4*k+1] = a.y; w[4*k+2] = a.z; w[4*k+3] = a.w;
        }
        #pragma unroll
        for (int k = 0; k < 16; ++k) {
            float4 a = wh[k];
            w[64+4*k+0] = a.x; w[64+4*k+1] = a.y; w[64+4*k+2] = a.z; w[64+4*k+3] = a.w;
        }
    }
    const float bi = b_ih[gr];
    const float bh = b_hh[gr];

    // ---- init h = 0 ----
    if (g == 0) v[64 + j] = 0.0f;
    float hcur = 0.0f;               // running h, owned by wave 0

    // ---- prefetch x for t=0 (wave 2 is the stager) ----
    float xr = 0.0f;
    if (g == 2) xr = X[(0 * BATCH + brow) * IDIM + j];

    const float4* v4 = (const float4*)v;

    for (int t = 0; t < T_STEPS; ++t) {
        if (g == 2) v[j] = xr;
        __syncthreads();   // barrier 1: x_t staged, h_{t-1} visible
        if (g == 2 && t + 1 < T_STEPS)
            xr = X[((t + 1) * BATCH + brow) * IDIM + j];   // hidden behind dots

        // ---- dots: aA over x-side (i in [0,64)), aB over h-side ----
        float aA0 = (g < 2) ? (bi + bh) : bi;
        float aB0 = (g == 2) ? bh : 0.0f;
        float aA1 = 0.0f, aB1 = 0.0f;
        #pragma unroll
        for (int k = 0; k < 8; ++k) {
            float4 p = v4[2*k];
            float4 q = v4[2*k + 1];
            aA0 = fmaf(p.x, w[8*k+0], aA0);
            aA0 = fmaf(p.y, w[8*k+1], aA0);
            aA0 = fmaf(p.z, w[8*k+2], aA0);
            aA0 = fmaf(p.w, w[8*k+3], aA0);
            aA1 = fmaf(q.x, w[8*k+4], aA1);
            aA1 = fmaf(q.y, w[8*k+5], aA1);
            aA1 = fmaf(q.z, w[8*k+6], aA1);
            aA1 = fmaf(q.w, w[8*k+7], aA1);
        }
        #pragma unroll
        for (int k = 0; k < 8; ++k) {
            float4 p = v4[16 + 2*k];
            float4 q = v4[16 + 2*k + 1];
            aB0 = fmaf(p.x, w[64+8*k+0], aB0);
            aB0 = fmaf(p.y, w[64+8*k+1], aB0);
            aB0 = fmaf(p.z, w[64+8*k+2], aB0);
            aB0 = fmaf(p.w, w[64+8*k+3], aB0);
            aB1 = fmaf(q.x, w[64+8*k+4], aB1);
            aB1 = fmaf(q.y, w[64+8*k+5], aB1);
            aB1 = fmaf(q.z, w[64+8*k+6], aB1);
            aB1 = fmaf(q.w, w[64+8*k+7], aB1);
        }
        const float aA = aA0 + aA1;
        const float aB = aB0 + aB1;

        if (g == 1)      { exZ[j]  = aA + aB; }
        else if (g == 2) { exNX[j] = aA; exNH[j] = aB; }
        const float rAcc = aA + aB;            // wave 0's r pre-activation
        __syncthreads();   // barrier 2: exchange visible

        if (g == 0) {
            const float r  = 1.0f / (1.0f + __expf(-rAcc));
            const float z  = 1.0f / (1.0f + __expf(-exZ[j]));
            const float np = exNX[j] + r * exNH[j];
            // tanh via stable formula: 1 - 2/(e^{2x}+1)  (inf-safe both tails)
            const float e  = __expf(2.0f * np);
            const float n  = 1.0f - 2.0f / (e + 1.0f);
            const float hn = (1.0f - z) * n + z * hcur;
            hcur = hn;
            v[64 + j] = hn;                              // h for next step
            out[(t * BATCH + brow) * HDIM + j] = hn;     // output[t]
        }
    }

    if (g == 0)
        out[T_STEPS * BATCH * HDIM + brow * HDIM + j] = hcur;  // h_last
}

extern "C" void kernel_launch(void* const* d_in, const int* in_sizes, int n_in,
                              void* d_out, int out_size, void* d_ws, size_t ws_size,
                              hipStream_t stream) {
    const float* X    = (const float*)d_in[0];
    const float* W_ih = (const float*)d_in[1];
    const float* W_hh = (const float*)d_in[2];
    const float* b_ih = (const float*)d_in[3];
    const float* b_hh = (const float*)d_in[4];
    float* out = (float*)d_out;

    dim3 grid(BATCH);
    dim3 block(192);
    gru_fused_kernel<<<grid, block, 0, stream>>>(X, W_ih, W_hh, b_ih, b_hh, out);
}